// Round 2
// baseline (129.688 us; speedup 1.0000x reference)
//
#include <hip/hip_runtime.h>
#include <math.h>

#define NB   1024
#define CH   60
#define SW   288
#define F1C  8
#define FD   16   // F1*D
#define F2C  16
#define KLEN 64
#define NCLS 4
#define PWID 72
#define NV   9
#define FEAT 144
#define NTHR 320

#define XR_STRIDE 356   // mult of 4 (b128 align); %32==4 -> uniform bank groups
#define PH_STRIDE 73
#define W1_STRIDE 68    // mult of 4; spreads 8 weight rows across bank groups

__device__ __forceinline__ float elu1(float v) {
    return v > 0.f ? v : __expf(v) - 1.f;   // native v_exp_f32, |abs err| ~1e-7
}

__global__ __launch_bounds__(NTHR, 5) void eegnet_main(
    const float* __restrict__ x, const int* __restrict__ y,
    const float* __restrict__ conv1_w,
    const float* __restrict__ bn1_g, const float* __restrict__ bn1_b,
    const float* __restrict__ bn1_m, const float* __restrict__ bn1_v,
    const float* __restrict__ dw_w,
    const float* __restrict__ bn2_g, const float* __restrict__ bn2_b,
    const float* __restrict__ bn2_m, const float* __restrict__ bn2_v,
    const float* __restrict__ pw_w,
    const float* __restrict__ bn3_g, const float* __restrict__ bn3_b,
    const float* __restrict__ bn3_m, const float* __restrict__ bn3_v,
    const float* __restrict__ fc_w, const float* __restrict__ fc_b,
    float* __restrict__ probs_out, float* __restrict__ feat_out,
    float* __restrict__ sums_out, int* __restrict__ cnt_out)
{
    __shared__ __align__(16) float s_xr[FD * XR_STRIDE];
    __shared__ __align__(16) float s_w1[F1C * W1_STRIDE];
    __shared__ float s_ph[FD * PH_STRIDE];
    __shared__ float s_pwT[FD * F2C];
    __shared__ float s_fc[NCLS * FEAT];
    __shared__ float s_feat[FEAT];
    __shared__ float s_A[FD], s_Cb[FD], s_a3[F2C], s_c3[F2C];

    const int tid = threadIdx.x;
    const int b = blockIdx.x;

    // ---- phase 0: stage weights, zero xr pads (no barrier needed before ph1) ----
    if (tid == 0) atomicAdd(&cnt_out[y[b]], 1);
    for (int i = tid; i < F1C * KLEN; i += NTHR)
        s_w1[(i >> 6) * W1_STRIDE + (i & 63)] = conv1_w[i];
    for (int i = tid; i < F2C * FD; i += NTHR)
        s_pwT[(i & 15) * F2C + (i >> 4)] = pw_w[i];
    for (int i = tid; i < NCLS * FEAT; i += NTHR) s_fc[i] = fc_w[i];
    for (int i = tid; i < FD * 68; i += NTHR) {     // pads: words [0,32) and [320,356)
        int f = i / 68, p = i % 68;
        int wp = (p < 32) ? p : (288 + p);
        s_xr[f * XR_STRIDE + wp] = 0.f;
    }
    if (tid < FD) {
        const int f = tid, f1 = f >> 1;
        const float inv1 = bn1_g[f1] / sqrtf(bn1_v[f1] + 1e-3f);
        const float c1 = bn1_b[f1] - bn1_m[f1] * inv1;
        const float inv2 = bn2_g[f] / sqrtf(bn2_v[f] + 1e-3f);
        const float c2 = bn2_b[f] - bn2_m[f] * inv2;
        float sdw = 0.f;
        for (int ch = 0; ch < CH; ++ch) sdw += dw_w[f * CH + ch];
        s_A[f] = inv2 * inv1;
        s_Cb[f] = inv2 * c1 * sdw + c2;
        const float inv3 = bn3_g[f] / sqrtf(bn3_v[f] + 1e-3f);
        s_a3[f] = inv3;
        s_c3[f] = bn3_b[f] - bn3_m[f] * inv3;
    }

    // ---- phase 1: xr[f][w] = sum_ch dw[f][ch]*x[b][ch][w]  (dw via SGPR s_loads) ----
    if (tid < SW) {
        const float* xb = x + (size_t)b * (CH * SW) + tid;
        float xv0[30], xv1[30];
        #pragma unroll
        for (int ch = 0; ch < 30; ++ch) xv0[ch] = xb[ch * SW];
        #pragma unroll
        for (int ch = 0; ch < 30; ++ch) xv1[ch] = xb[(30 + ch) * SW];
        float acc[FD];
        #pragma unroll
        for (int f = 0; f < FD; ++f) acc[f] = 0.f;
        #pragma unroll
        for (int ch = 0; ch < 30; ++ch) {
            const float v = xv0[ch];
            #pragma unroll
            for (int f = 0; f < FD; ++f)
                acc[f] = fmaf(dw_w[f * CH + ch], v, acc[f]);   // uniform -> s_load
        }
        #pragma unroll
        for (int ch = 0; ch < 30; ++ch) {
            const float v = xv1[ch];
            #pragma unroll
            for (int f = 0; f < FD; ++f)
                acc[f] = fmaf(dw_w[f * CH + 30 + ch], v, acc[f]);
        }
        #pragma unroll
        for (int f = 0; f < FD; ++f) s_xr[f * XR_STRIDE + 32 + tid] = acc[f];
    }
    __syncthreads();

    // ---- phase 2: K=64 conv + bn2 + elu + pool4 via b128 rolling window ----
    if (tid < 288) {
        const int f = tid & 15;
        const float4* wq = (const float4*)&s_w1[(f >> 1) * W1_STRIDE];
        const float Af = s_A[f], Cf = s_Cb[f];
        #pragma unroll
        for (int r = 0; r < 2; ++r) {
            const int pp = (tid >> 4) + r * 18;      // 0..35
            const int U = 2 * pp;                    // even pool index
            const float4* xp = (const float4*)&s_xr[f * XR_STRIDE + 4 * U];
            float4 c0 = xp[0], c1 = xp[1];
            float b0 = 0.f, b1 = 0.f, b2 = 0.f, b3 = 0.f;
            float b4 = 0.f, b5 = 0.f, b6 = 0.f, b7 = 0.f;
            #pragma unroll
            for (int m = 0; m < 16; ++m) {
                const float4 c2 = xp[m + 2];
                const float4 wv = wq[m];
                b0 = fmaf(wv.x, c0.x, b0); b0 = fmaf(wv.y, c0.y, b0);
                b0 = fmaf(wv.z, c0.z, b0); b0 = fmaf(wv.w, c0.w, b0);
                b1 = fmaf(wv.x, c0.y, b1); b1 = fmaf(wv.y, c0.z, b1);
                b1 = fmaf(wv.z, c0.w, b1); b1 = fmaf(wv.w, c1.x, b1);
                b2 = fmaf(wv.x, c0.z, b2); b2 = fmaf(wv.y, c0.w, b2);
                b2 = fmaf(wv.z, c1.x, b2); b2 = fmaf(wv.w, c1.y, b2);
                b3 = fmaf(wv.x, c0.w, b3); b3 = fmaf(wv.y, c1.x, b3);
                b3 = fmaf(wv.z, c1.y, b3); b3 = fmaf(wv.w, c1.z, b3);
                b4 = fmaf(wv.x, c1.x, b4); b4 = fmaf(wv.y, c1.y, b4);
                b4 = fmaf(wv.z, c1.z, b4); b4 = fmaf(wv.w, c1.w, b4);
                b5 = fmaf(wv.x, c1.y, b5); b5 = fmaf(wv.y, c1.z, b5);
                b5 = fmaf(wv.z, c1.w, b5); b5 = fmaf(wv.w, c2.x, b5);
                b6 = fmaf(wv.x, c1.z, b6); b6 = fmaf(wv.y, c1.w, b6);
                b6 = fmaf(wv.z, c2.x, b6); b6 = fmaf(wv.w, c2.y, b6);
                b7 = fmaf(wv.x, c1.w, b7); b7 = fmaf(wv.y, c2.x, b7);
                b7 = fmaf(wv.z, c2.y, b7); b7 = fmaf(wv.w, c2.z, b7);
                c0 = c1; c1 = c2;
            }
            const float e0 = elu1(fmaf(Af, b0, Cf));
            const float e1 = elu1(fmaf(Af, b1, Cf));
            const float e2 = elu1(fmaf(Af, b2, Cf));
            const float e3 = elu1(fmaf(Af, b3, Cf));
            const float e4 = elu1(fmaf(Af, b4, Cf));
            const float e5 = elu1(fmaf(Af, b5, Cf));
            const float e6 = elu1(fmaf(Af, b6, Cf));
            const float e7 = elu1(fmaf(Af, b7, Cf));
            s_ph[f * PH_STRIDE + U]     = (e0 + e1 + e2 + e3) * 0.25f;
            s_ph[f * PH_STRIDE + U + 1] = (e4 + e5 + e6 + e7) * 0.25f;
        }
    }
    __syncthreads();

    // ---- phase 3: pointwise 16x16 + bn3 + elu + pool8 -> feat[144] ----
    if (tid < FEAT) {
        const int f2 = tid / NV;
        const int v = tid - f2 * NV;
        const float a3f = s_a3[f2], c3f = s_c3[f2];
        float acc = 0.f;
        #pragma unroll
        for (int u8 = 0; u8 < 8; ++u8) {
            const int u = v * 8 + u8;
            float s = 0.f;
            #pragma unroll
            for (int f = 0; f < FD; ++f)
                s = fmaf(s_pwT[f * F2C + f2], s_ph[f * PH_STRIDE + u], s);
            acc += elu1(fmaf(a3f, s, c3f));
        }
        const float ft = acc * 0.125f;
        s_feat[tid] = ft;
        feat_out[(size_t)b * FEAT + tid] = ft;
        atomicAdd(&sums_out[y[b] * FEAT + tid], ft);
    }
    __syncthreads();

    // ---- phase 4: logits + softmax (wave 0) ----
    if (tid < 64) {
        float lg0 = 0.f, lg1 = 0.f, lg2 = 0.f, lg3 = 0.f;
        for (int j = tid; j < FEAT; j += 64) {
            const float fv = s_feat[j];
            lg0 = fmaf(fv, s_fc[0 * FEAT + j], lg0);
            lg1 = fmaf(fv, s_fc[1 * FEAT + j], lg1);
            lg2 = fmaf(fv, s_fc[2 * FEAT + j], lg2);
            lg3 = fmaf(fv, s_fc[3 * FEAT + j], lg3);
        }
        #pragma unroll
        for (int off = 32; off > 0; off >>= 1) {
            lg0 += __shfl_down(lg0, off, 64);
            lg1 += __shfl_down(lg1, off, 64);
            lg2 += __shfl_down(lg2, off, 64);
            lg3 += __shfl_down(lg3, off, 64);
        }
        if (tid == 0) {
            lg0 += fc_b[0]; lg1 += fc_b[1]; lg2 += fc_b[2]; lg3 += fc_b[3];
            const float m = fmaxf(fmaxf(lg0, lg1), fmaxf(lg2, lg3));
            const float e0 = __expf(lg0 - m), e1 = __expf(lg1 - m);
            const float e2 = __expf(lg2 - m), e3 = __expf(lg3 - m);
            const float inv = 1.f / (e0 + e1 + e2 + e3);
            float* po = probs_out + (size_t)b * NCLS;
            po[0] = e0 * inv; po[1] = e1 * inv; po[2] = e2 * inv; po[3] = e3 * inv;
        }
    }
}

__global__ __launch_bounds__(256) void eegnet_dist(
    const float* __restrict__ feat, const int* __restrict__ y,
    const float* __restrict__ sums, const int* __restrict__ cnt,
    float* __restrict__ cl_out)
{
    __shared__ float s_cent[NCLS * FEAT];
    __shared__ float s_red[4];
    const int tid = threadIdx.x;
    for (int i = tid; i < NCLS * FEAT; i += 256)
        s_cent[i] = sums[i] / fmaxf((float)cnt[i / FEAT], 1.0f);
    __syncthreads();

    const int s = blockIdx.x * 256 + tid;
    const float* fp = feat + (size_t)s * FEAT;
    const float* cp = &s_cent[y[s] * FEAT];
    float acc = 0.f;
    #pragma unroll
    for (int j = 0; j < FEAT; j += 4) {
        const float4 fv = *reinterpret_cast<const float4*>(fp + j);
        float d;
        d = fv.x - cp[j + 0] + 1e-6f; acc = fmaf(d, d, acc);
        d = fv.y - cp[j + 1] + 1e-6f; acc = fmaf(d, d, acc);
        d = fv.z - cp[j + 2] + 1e-6f; acc = fmaf(d, d, acc);
        d = fv.w - cp[j + 3] + 1e-6f; acc = fmaf(d, d, acc);
    }
    float dist = sqrtf(acc);
    #pragma unroll
    for (int off = 32; off > 0; off >>= 1) dist += __shfl_down(dist, off, 64);
    if ((tid & 63) == 0) s_red[tid >> 6] = dist;
    __syncthreads();
    if (tid == 0) {
        const float t = s_red[0] + s_red[1] + s_red[2] + s_red[3];
        atomicAdd(cl_out, t * (1.0f / 1024.0f));
    }
}

extern "C" void kernel_launch(void* const* d_in, const int* in_sizes, int n_in,
                              void* d_out, int out_size, void* d_ws, size_t ws_size,
                              hipStream_t stream) {
    const float* x       = (const float*)d_in[0];
    const int*   y       = (const int*)d_in[1];
    const float* conv1_w = (const float*)d_in[2];
    const float* bn1_g   = (const float*)d_in[3];
    const float* bn1_b   = (const float*)d_in[4];
    const float* bn1_m   = (const float*)d_in[5];
    const float* bn1_v   = (const float*)d_in[6];
    const float* dw_w    = (const float*)d_in[7];
    const float* bn2_g   = (const float*)d_in[8];
    const float* bn2_b   = (const float*)d_in[9];
    const float* bn2_m   = (const float*)d_in[10];
    const float* bn2_v   = (const float*)d_in[11];
    const float* pw_w    = (const float*)d_in[12];
    const float* bn3_g   = (const float*)d_in[13];
    const float* bn3_b   = (const float*)d_in[14];
    const float* bn3_m   = (const float*)d_in[15];
    const float* bn3_v   = (const float*)d_in[16];
    const float* fc_w    = (const float*)d_in[17];
    const float* fc_b    = (const float*)d_in[18];

    float* out   = (float*)d_out;
    float* probs = out;                       // [1024*4]
    float* cl    = out + 4096;                // [1]
    float* sums  = (float*)d_ws;              // 576 floats
    int*   cnt   = (int*)((char*)d_ws + 2304);// 4 ints
    float* feat  = (float*)((char*)d_ws + 2560); // 1024*144 floats, 16B-aligned

    hipMemsetAsync(d_ws, 0, 2320, stream);            // sums + cnt
    hipMemsetAsync(cl, 0, sizeof(float), stream);     // loss accumulator
    eegnet_main<<<NB, NTHR, 0, stream>>>(
        x, y, conv1_w, bn1_g, bn1_b, bn1_m, bn1_v,
        dw_w, bn2_g, bn2_b, bn2_m, bn2_v,
        pw_w, bn3_g, bn3_b, bn3_m, bn3_v,
        fc_w, fc_b, probs, feat, sums, cnt);
    eegnet_dist<<<NB / 256, 256, 0, stream>>>(feat, y, sums, cnt, cl);
}

// Round 3
// 66.010 us; speedup vs baseline: 1.9647x; 1.9647x over previous
//
#include <hip/hip_runtime.h>
#include <math.h>

#define NB   1024
#define CH   60
#define SW   288
#define F1C  8
#define FD   16   // F1*D
#define F2C  16
#define KLEN 64
#define NCLS 4
#define PWID 72
#define NV   9
#define FEAT 144
#define NTHR 320

#define XR_STRIDE 356   // mult of 4 (b128-aligned rows)
#define PH_STRIDE 76    // mult of 4
#define W1_STRIDE 68    // mult of 4

__device__ __forceinline__ float elu1(float v) {
    return v > 0.f ? v : __expf(v) - 1.f;   // native v_exp_f32
}

__global__ __launch_bounds__(NTHR, 4) void eegnet_main(
    const float* __restrict__ x, const int* __restrict__ y,
    const float* __restrict__ conv1_w,
    const float* __restrict__ bn1_g, const float* __restrict__ bn1_b,
    const float* __restrict__ bn1_m, const float* __restrict__ bn1_v,
    const float* __restrict__ dw_w,
    const float* __restrict__ bn2_g, const float* __restrict__ bn2_b,
    const float* __restrict__ bn2_m, const float* __restrict__ bn2_v,
    const float* __restrict__ pw_w,
    const float* __restrict__ bn3_g, const float* __restrict__ bn3_b,
    const float* __restrict__ bn3_m, const float* __restrict__ bn3_v,
    const float* __restrict__ fc_w, const float* __restrict__ fc_b,
    float* __restrict__ probs_out, float* __restrict__ feat_out,
    float* __restrict__ sums_out, int* __restrict__ cnt_out)
{
    __shared__ __align__(16) float s_xr[FD * XR_STRIDE];
    __shared__ __align__(16) float s_w1[F1C * W1_STRIDE];
    __shared__ __align__(16) float s_ph[FD * PH_STRIDE];
    __shared__ float s_pwT[FD * F2C];
    __shared__ float s_fc[NCLS * FEAT];
    __shared__ float s_feat[FEAT];
    __shared__ float s_A[FD], s_Cb[FD], s_a3[F2C], s_c3[F2C];

    const int tid = threadIdx.x;
    const int b = blockIdx.x;

    // ---- phase 0: stage weights, zero xr pads ----
    if (tid == 0) atomicAdd(&cnt_out[y[b]], 1);
    for (int i = tid; i < F1C * KLEN; i += NTHR)
        s_w1[(i >> 6) * W1_STRIDE + (i & 63)] = conv1_w[i];
    for (int i = tid; i < F2C * FD; i += NTHR)
        s_pwT[(i & 15) * F2C + (i >> 4)] = pw_w[i];
    for (int i = tid; i < NCLS * FEAT; i += NTHR) s_fc[i] = fc_w[i];
    for (int i = tid; i < FD * 68; i += NTHR) {     // pads: words [0,32) and [320,356)
        int f = i / 68, p = i % 68;
        int wp = (p < 32) ? p : (288 + p);
        s_xr[f * XR_STRIDE + wp] = 0.f;
    }
    if (tid < FD) {
        const int f = tid, f1 = f >> 1;
        const float inv1 = bn1_g[f1] / sqrtf(bn1_v[f1] + 1e-3f);
        const float c1 = bn1_b[f1] - bn1_m[f1] * inv1;
        const float inv2 = bn2_g[f] / sqrtf(bn2_v[f] + 1e-3f);
        const float c2 = bn2_b[f] - bn2_m[f] * inv2;
        float sdw = 0.f;
        for (int ch = 0; ch < CH; ++ch) sdw += dw_w[f * CH + ch];
        s_A[f] = inv2 * inv1;
        s_Cb[f] = inv2 * c1 * sdw + c2;
        const float inv3 = bn3_g[f] / sqrtf(bn3_v[f] + 1e-3f);
        s_a3[f] = inv3;
        s_c3[f] = bn3_b[f] - bn3_m[f] * inv3;
    }

    // ---- phase 1: xr[f][w] = sum_ch dw[f][ch]*x[b][ch][w] ----
    // dw_w indices are wave-uniform -> SGPR s_loads (no LDS, no VGPR cost).
    // x prefetched in 12-deep double-buffered chunks: ~48 live VGPRs, no spill.
    if (tid < SW) {
        const float* xb = x + (size_t)b * (CH * SW) + tid;
        float acc[FD];
        #pragma unroll
        for (int f = 0; f < FD; ++f) acc[f] = 0.f;
        float xa[12];
        #pragma unroll
        for (int j = 0; j < 12; ++j) xa[j] = xb[j * SW];
        #pragma unroll
        for (int c0 = 0; c0 < CH; c0 += 12) {
            float xn[12];
            if (c0 + 12 < CH) {
                #pragma unroll
                for (int j = 0; j < 12; ++j) xn[j] = xb[(c0 + 12 + j) * SW];
            }
            #pragma unroll
            for (int j = 0; j < 12; ++j) {
                const float v = xa[j];
                #pragma unroll
                for (int f = 0; f < FD; ++f)
                    acc[f] = fmaf(dw_w[f * CH + c0 + j], v, acc[f]);
            }
            if (c0 + 12 < CH) {
                #pragma unroll
                for (int j = 0; j < 12; ++j) xa[j] = xn[j];
            }
        }
        #pragma unroll
        for (int f = 0; f < FD; ++f) s_xr[f * XR_STRIDE + 32 + tid] = acc[f];
    }
    __syncthreads();

    // ---- phase 2: K=64 conv + bn2 + elu + pool4, 16 conv outputs/thread ----
    // circular 20-float register window, all indices compile-time (SROA-safe)
    if (tid < 288) {
        const int f = tid & 15;
        const int q = tid >> 4;                   // 0..17
        const float4* xp = (const float4*)&s_xr[f * XR_STRIDE + 16 * q];
        const float4* wp = (const float4*)&s_w1[(f >> 1) * W1_STRIDE];
        float cw[20];
        #pragma unroll
        for (int i = 0; i < 4; ++i) {
            const float4 t = xp[i];
            cw[4*i] = t.x; cw[4*i+1] = t.y; cw[4*i+2] = t.z; cw[4*i+3] = t.w;
        }
        float bb[16];
        #pragma unroll
        for (int j = 0; j < 16; ++j) bb[j] = 0.f;
        #pragma unroll
        for (int m = 0; m < 16; ++m) {
            {
                const float4 t = xp[m + 4];
                const int s = (4 * (m + 4)) % 20;     // mult of 4, never wraps mid-vec
                cw[s] = t.x; cw[s+1] = t.y; cw[s+2] = t.z; cw[s+3] = t.w;
            }
            const float4 wv = wp[m];
            #pragma unroll
            for (int j = 0; j < 16; ++j) {
                bb[j] = fmaf(wv.x, cw[(4*m + j    ) % 20], bb[j]);
                bb[j] = fmaf(wv.y, cw[(4*m + j + 1) % 20], bb[j]);
                bb[j] = fmaf(wv.z, cw[(4*m + j + 2) % 20], bb[j]);
                bb[j] = fmaf(wv.w, cw[(4*m + j + 3) % 20], bb[j]);
            }
        }
        const float Af = s_A[f], Cf = s_Cb[f];
        float e[16];
        #pragma unroll
        for (int j = 0; j < 16; ++j) e[j] = elu1(fmaf(Af, bb[j], Cf));
        float4 ph;
        ph.x = (e[0]  + e[1]  + e[2]  + e[3])  * 0.25f;
        ph.y = (e[4]  + e[5]  + e[6]  + e[7])  * 0.25f;
        ph.z = (e[8]  + e[9]  + e[10] + e[11]) * 0.25f;
        ph.w = (e[12] + e[13] + e[14] + e[15]) * 0.25f;
        *(float4*)&s_ph[f * PH_STRIDE + 4 * q] = ph;
    }
    __syncthreads();

    // ---- phase 3: pointwise 16x16 + bn3 + elu + pool8 -> feat[144] ----
    if (tid < FEAT) {
        const int f2 = tid / NV;
        const int v = tid - f2 * NV;
        float su[8];
        #pragma unroll
        for (int k = 0; k < 8; ++k) su[k] = 0.f;
        #pragma unroll
        for (int f = 0; f < FD; ++f) {
            const float w = s_pwT[f * F2C + f2];
            const float4 p0 = *(const float4*)&s_ph[f * PH_STRIDE + 8 * v];
            const float4 p1 = *(const float4*)&s_ph[f * PH_STRIDE + 8 * v + 4];
            su[0] = fmaf(w, p0.x, su[0]); su[1] = fmaf(w, p0.y, su[1]);
            su[2] = fmaf(w, p0.z, su[2]); su[3] = fmaf(w, p0.w, su[3]);
            su[4] = fmaf(w, p1.x, su[4]); su[5] = fmaf(w, p1.y, su[5]);
            su[6] = fmaf(w, p1.z, su[6]); su[7] = fmaf(w, p1.w, su[7]);
        }
        const float a3f = s_a3[f2], c3f = s_c3[f2];
        float acc = 0.f;
        #pragma unroll
        for (int k = 0; k < 8; ++k) acc += elu1(fmaf(a3f, su[k], c3f));
        const float ft = acc * 0.125f;
        s_feat[tid] = ft;
        feat_out[(size_t)b * FEAT + tid] = ft;
        atomicAdd(&sums_out[y[b] * FEAT + tid], ft);
    }
    __syncthreads();

    // ---- phase 4: logits + softmax (wave 0) ----
    if (tid < 64) {
        float lg0 = 0.f, lg1 = 0.f, lg2 = 0.f, lg3 = 0.f;
        for (int j = tid; j < FEAT; j += 64) {
            const float fv = s_feat[j];
            lg0 = fmaf(fv, s_fc[0 * FEAT + j], lg0);
            lg1 = fmaf(fv, s_fc[1 * FEAT + j], lg1);
            lg2 = fmaf(fv, s_fc[2 * FEAT + j], lg2);
            lg3 = fmaf(fv, s_fc[3 * FEAT + j], lg3);
        }
        #pragma unroll
        for (int off = 32; off > 0; off >>= 1) {
            lg0 += __shfl_down(lg0, off, 64);
            lg1 += __shfl_down(lg1, off, 64);
            lg2 += __shfl_down(lg2, off, 64);
            lg3 += __shfl_down(lg3, off, 64);
        }
        if (tid == 0) {
            lg0 += fc_b[0]; lg1 += fc_b[1]; lg2 += fc_b[2]; lg3 += fc_b[3];
            const float m = fmaxf(fmaxf(lg0, lg1), fmaxf(lg2, lg3));
            const float e0 = __expf(lg0 - m), e1 = __expf(lg1 - m);
            const float e2 = __expf(lg2 - m), e3 = __expf(lg3 - m);
            const float inv = 1.f / (e0 + e1 + e2 + e3);
            float* po = probs_out + (size_t)b * NCLS;
            po[0] = e0 * inv; po[1] = e1 * inv; po[2] = e2 * inv; po[3] = e3 * inv;
        }
    }
}

__global__ __launch_bounds__(256) void eegnet_dist(
    const float* __restrict__ feat, const int* __restrict__ y,
    const float* __restrict__ sums, const int* __restrict__ cnt,
    float* __restrict__ cl_out)
{
    __shared__ float s_cent[NCLS * FEAT];
    __shared__ float s_red[4];
    const int tid = threadIdx.x;
    for (int i = tid; i < NCLS * FEAT; i += 256)
        s_cent[i] = sums[i] / fmaxf((float)cnt[i / FEAT], 1.0f);
    __syncthreads();

    const int s = blockIdx.x * 256 + tid;
    const float* fp = feat + (size_t)s * FEAT;
    const float* cp = &s_cent[y[s] * FEAT];
    float acc = 0.f;
    #pragma unroll
    for (int j = 0; j < FEAT; j += 4) {
        const float4 fv = *reinterpret_cast<const float4*>(fp + j);
        float d;
        d = fv.x - cp[j + 0] + 1e-6f; acc = fmaf(d, d, acc);
        d = fv.y - cp[j + 1] + 1e-6f; acc = fmaf(d, d, acc);
        d = fv.z - cp[j + 2] + 1e-6f; acc = fmaf(d, d, acc);
        d = fv.w - cp[j + 3] + 1e-6f; acc = fmaf(d, d, acc);
    }
    float dist = sqrtf(acc);
    #pragma unroll
    for (int off = 32; off > 0; off >>= 1) dist += __shfl_down(dist, off, 64);
    if ((tid & 63) == 0) s_red[tid >> 6] = dist;
    __syncthreads();
    if (tid == 0) {
        const float t = s_red[0] + s_red[1] + s_red[2] + s_red[3];
        atomicAdd(cl_out, t * (1.0f / 1024.0f));
    }
}

extern "C" void kernel_launch(void* const* d_in, const int* in_sizes, int n_in,
                              void* d_out, int out_size, void* d_ws, size_t ws_size,
                              hipStream_t stream) {
    const float* x       = (const float*)d_in[0];
    const int*   y       = (const int*)d_in[1];
    const float* conv1_w = (const float*)d_in[2];
    const float* bn1_g   = (const float*)d_in[3];
    const float* bn1_b   = (const float*)d_in[4];
    const float* bn1_m   = (const float*)d_in[5];
    const float* bn1_v   = (const float*)d_in[6];
    const float* dw_w    = (const float*)d_in[7];
    const float* bn2_g   = (const float*)d_in[8];
    const float* bn2_b   = (const float*)d_in[9];
    const float* bn2_m   = (const float*)d_in[10];
    const float* bn2_v   = (const float*)d_in[11];
    const float* pw_w    = (const float*)d_in[12];
    const float* bn3_g   = (const float*)d_in[13];
    const float* bn3_b   = (const float*)d_in[14];
    const float* bn3_m   = (const float*)d_in[15];
    const float* bn3_v   = (const float*)d_in[16];
    const float* fc_w    = (const float*)d_in[17];
    const float* fc_b    = (const float*)d_in[18];

    float* out   = (float*)d_out;
    float* probs = out;                       // [1024*4]
    float* cl    = out + 4096;                // [1]
    float* sums  = (float*)d_ws;              // 576 floats
    int*   cnt   = (int*)((char*)d_ws + 2304);// 4 ints
    float* feat  = (float*)((char*)d_ws + 2560); // 1024*144 floats, 16B-aligned

    hipMemsetAsync(d_ws, 0, 2320, stream);            // sums + cnt
    hipMemsetAsync(cl, 0, sizeof(float), stream);     // loss accumulator
    eegnet_main<<<NB, NTHR, 0, stream>>>(
        x, y, conv1_w, bn1_g, bn1_b, bn1_m, bn1_v,
        dw_w, bn2_g, bn2_b, bn2_m, bn2_v,
        pw_w, bn3_g, bn3_b, bn3_m, bn3_v,
        fc_w, fc_b, probs, feat, sums, cnt);
    eegnet_dist<<<NB / 256, 256, 0, stream>>>(feat, y, sums, cnt, cl);
}